// Round 6
// baseline (116.704 us; speedup 1.0000x reference)
//
#include <hip/hip_runtime.h>
#include <hip/hip_bf16.h>
#include <stdint.h>

typedef unsigned short u16;
typedef __attribute__((ext_vector_type(8))) __bf16 bf16x8;
typedef __attribute__((ext_vector_type(4))) float f32x4;
typedef __attribute__((ext_vector_type(16))) float f32x16;

#define AS1(p) ((const __attribute__((address_space(1))) void*)(p))
#define AS3(p) ((__attribute__((address_space(3))) void*)(p))

__device__ __forceinline__ u16 f2bf(float f) {
  union { float f; uint32_t u; } c; c.f = f;
  uint32_t u = c.u;
  u += 0x7fffu + ((u >> 16) & 1u);   // RTNE
  return (u16)(u >> 16);
}

__device__ __forceinline__ float exp2_fast(float x) {
  float r; asm("v_exp_f32 %0, %1" : "=v"(r) : "v"(x)); return r;
}

__device__ __forceinline__ unsigned pkbf(float lo, float hi) {
  unsigned r;
  asm("v_cvt_pk_bf16_f32 %0, %1, %2" : "=v"(r) : "v"(lo), "v"(hi));
  return r;
}

// ---------------- fused cast+GEMM: C[M][N] = scale * (A_f32[M][K] . B_f32[N][K]^T) -> bf16 ----
// 128x128 tile, BK=32, 256 thr, reg-staged fp32->bf16 (cast fused), double-buffered LDS,
// XOR-swizzled rows (2-way write / 2-way read, free per m136). Raw s_barrier + lgkmcnt only —
// global loads for t+1 stay in flight across the barriers (no vmcnt drain).
// Blocks 0..255: q = scale_q * x.Wq^T (M=4096,N=1024). 256..767: kv = ctx.Wkv^T (N=2048).
__global__ __launch_bounds__(256, 3) void gemm_fused(const float* __restrict__ xf,
                                                     const float* __restrict__ wqf,
                                                     u16* __restrict__ qo,
                                                     const float* __restrict__ cf,
                                                     const float* __restrict__ wkf,
                                                     u16* __restrict__ kvo,
                                                     float scale_q) {
  __shared__ u16 As[2][128 * 32];
  __shared__ u16 Bs[2][128 * 32];
  const int K = 1024;
  int bid = blockIdx.x;
  const float *A, *B; u16* C; int N, bm, bn; float scale;
  if (bid < 256) { A = xf; B = wqf; C = qo;  N = 1024; bm = bid >> 3; bn = bid & 7;  scale = scale_q; }
  else { int b2 = bid - 256; A = cf; B = wkf; C = kvo; N = 2048; bm = b2 >> 4; bn = b2 & 15; scale = 1.0f; }

  int tid = threadIdx.x;
  int w = tid >> 6, l = tid & 63;
  int wr = w >> 1, wc = w & 1;
  int lr = l & 15, lg = l >> 4;

  // staging assignment: thread -> (row ra, 16-col chunk ca); 128 rows x 2 chunks
  int ra = tid >> 1, ca = tid & 1;
  const float* Ag = A + (size_t)(bm * 128 + ra) * K + ca * 16;
  const float* Bg = B + (size_t)(bn * 128 + ra) * K + ca * 16;
  int swz8 = ((ra >> 1) & 3) << 3;   // u16-index swizzle (16B-slot XOR within 64B row)

  f32x4 acc[4][4];
#pragma unroll
  for (int i = 0; i < 4; ++i)
#pragma unroll
    for (int j = 0; j < 4; ++j) acc[i][j] = (f32x4){0.f, 0.f, 0.f, 0.f};

  // prologue: issue loads for k=0 (8 x dwordx4)
  float4 a0 = *(const float4*)(Ag + 0),  a1 = *(const float4*)(Ag + 4);
  float4 a2 = *(const float4*)(Ag + 8),  a3 = *(const float4*)(Ag + 12);
  float4 b0 = *(const float4*)(Bg + 0),  b1 = *(const float4*)(Bg + 4);
  float4 b2 = *(const float4*)(Bg + 8),  b3 = *(const float4*)(Bg + 12);

  for (int t = 0; t < 32; ++t) {
    int cur = t & 1;
    // ---- cvt fp32->bf16 (fused cast) + swizzled LDS write (compiler waits vmcnt here)
    uint4 pA0, pA1, pB0, pB1;
    pA0.x = pkbf(a0.x, a0.y); pA0.y = pkbf(a0.z, a0.w);
    pA0.z = pkbf(a1.x, a1.y); pA0.w = pkbf(a1.z, a1.w);
    pA1.x = pkbf(a2.x, a2.y); pA1.y = pkbf(a2.z, a2.w);
    pA1.z = pkbf(a3.x, a3.y); pA1.w = pkbf(a3.z, a3.w);
    pB0.x = pkbf(b0.x, b0.y); pB0.y = pkbf(b0.z, b0.w);
    pB0.z = pkbf(b1.x, b1.y); pB0.w = pkbf(b1.z, b1.w);
    pB1.x = pkbf(b2.x, b2.y); pB1.y = pkbf(b2.z, b2.w);
    pB1.z = pkbf(b3.x, b3.y); pB1.w = pkbf(b3.z, b3.w);
    *(uint4*)(&As[cur][ra * 32 + ((ca * 16 + 0) ^ swz8)]) = pA0;
    *(uint4*)(&As[cur][ra * 32 + ((ca * 16 + 8) ^ swz8)]) = pA1;
    *(uint4*)(&Bs[cur][ra * 32 + ((ca * 16 + 0) ^ swz8)]) = pB0;
    *(uint4*)(&Bs[cur][ra * 32 + ((ca * 16 + 8) ^ swz8)]) = pB1;
    // ---- issue loads for t+1 (in flight across barriers + compute)
    if (t < 31) {
      const float* An = Ag + (t + 1) * 32;
      const float* Bn = Bg + (t + 1) * 32;
      a0 = *(const float4*)(An + 0);  a1 = *(const float4*)(An + 4);
      a2 = *(const float4*)(An + 8);  a3 = *(const float4*)(An + 12);
      b0 = *(const float4*)(Bn + 0);  b1 = *(const float4*)(Bn + 4);
      b2 = *(const float4*)(Bn + 8);  b3 = *(const float4*)(Bn + 12);
    }
    asm volatile("s_waitcnt lgkmcnt(0)" ::: "memory");   // my ds_writes committed
    __builtin_amdgcn_s_barrier();                        // tile visible to all waves
    // ---- fragments (swizzled read: 2-way max)
    bf16x8 af[4], bb[4];
#pragma unroll
    for (int i = 0; i < 4; ++i) {
      int row = wr * 64 + i * 16 + lr;
      af[i] = *(const bf16x8*)(&As[cur][row * 32 + ((lg * 8) ^ (((row >> 1) & 3) << 3))]);
    }
#pragma unroll
    for (int j = 0; j < 4; ++j) {
      int row = wc * 64 + j * 16 + lr;
      bb[j] = *(const bf16x8*)(&Bs[cur][row * 32 + ((lg * 8) ^ (((row >> 1) & 3) << 3))]);
    }
    asm volatile("s_waitcnt lgkmcnt(0)" ::: "memory");
    __builtin_amdgcn_sched_barrier(0);                   // rule 18
#pragma unroll
    for (int i = 0; i < 4; ++i)
#pragma unroll
      for (int j = 0; j < 4; ++j)
        acc[i][j] = __builtin_amdgcn_mfma_f32_16x16x32_bf16(af[i], bb[j], acc[i][j], 0, 0, 0);
    __builtin_amdgcn_s_barrier();                        // reads done before buf reuse (t+2)
  }

#pragma unroll
  for (int i = 0; i < 4; ++i)
#pragma unroll
    for (int j = 0; j < 4; ++j)
#pragma unroll
      for (int r = 0; r < 4; ++r) {
        int row = bm * 128 + wr * 64 + i * 16 + lg * 4 + r;
        int col = bn * 128 + wc * 64 + j * 16 + lr;
        C[(size_t)row * N + col] = f2bf(acc[i][j][r] * scale);
      }
}

// ---------------- flash attention: T15 double-pipeline, 32x32 swapped QK^T ----------------
// grid = 512 blocks (2/CU), 256 thr (4 waves x 32 q-rows). One barrier per tile.
#define SQ 2048
#define NT 32

__global__ __launch_bounds__(256, 2) void attn_kernel(const u16* __restrict__ Q,
                                                      const u16* __restrict__ KV,
                                                      float* __restrict__ O) {
  __shared__ u16 Ks[2 * 64 * 64];  // [buf][j][d], 16B-block bk holds dblk = bk ^ (j&7)
  __shared__ u16 Vt[2 * 64 * 64];  // [buf][d][j], byte = d*128 + ((j*2) ^ (((d^(d>>3))&7)<<4))

  int qt = blockIdx.x & 15;
  int bh = blockIdx.x >> 4;
  int b = bh >> 4, h = bh & 15;
  int tid = threadIdx.x;
  int w = tid >> 6, l = tid & 63;
  int li = l & 31, hi = l >> 5;
  int jr = l >> 3, bk = l & 7;

  const u16* kbase = KV + (size_t)b * SQ * 2048 + (size_t)h * 64;
  const u16* vbase = kbase + 1024;
  int i0g = qt * 128 + w * 32;
  const u16* qrow = Q + (size_t)(b * SQ + i0g + li) * 1024 + h * 64;

  bf16x8 qf0 = *(const bf16x8*)(qrow + 0  + hi * 8);
  bf16x8 qf1 = *(const bf16x8*)(qrow + 16 + hi * 8);
  bf16x8 qf2 = *(const bf16x8*)(qrow + 32 + hi * 8);
  bf16x8 qf3 = *(const bf16x8*)(qrow + 48 + hi * 8);

  // prologue: stage tile 0
  {
    const u16* gk0 = kbase + (size_t)(w * 8 + jr) * 2048 + ((bk ^ jr) * 8);
    __builtin_amdgcn_global_load_lds(AS1(gk0), AS3(Ks + w * 512), 16, 0, 0);
    const u16* gk1 = kbase + (size_t)(32 + w * 8 + jr) * 2048 + ((bk ^ jr) * 8);
    __builtin_amdgcn_global_load_lds(AS1(gk1), AS3(Ks + 2048 + w * 512), 16, 0, 0);
  }
  uint4 vregA = *(const uint4*)(vbase + (size_t)(tid >> 3) * 2048 + (tid & 7) * 8);
  uint4 vregB = *(const uint4*)(vbase + (size_t)(32 + (tid >> 3)) * 2048 + (tid & 7) * 8);

  float m_run = -1e30f, l_run = 0.f;
  f32x16 acc0, acc1;
#pragma unroll
  for (int r = 0; r < 16; ++r) { acc0[r] = 0.f; acc1[r] = 0.f; }

  auto stage_pf = [&](int t) {
    u16* Vtc = Vt + (t & 1) * 4096;
    int a = tid & 7, jj0 = tid >> 3;
    const u16* pa_ = (const u16*)&vregA;
#pragma unroll
    for (int e = 0; e < 8; ++e)
      *(u16*)((char*)Vtc + (a * 8 + e) * 128 + ((jj0 * 2) ^ ((e ^ a) << 4))) = pa_[e];
    const u16* pb_ = (const u16*)&vregB;
    int jj1 = 32 + jj0;
#pragma unroll
    for (int e = 0; e < 8; ++e)
      *(u16*)((char*)Vtc + (a * 8 + e) * 128 + ((jj1 * 2) ^ ((e ^ a) << 4))) = pb_[e];
    if (t + 1 < NT) {
      int j0n = (t + 1) * 64;
      u16* Ksn = Ks + ((t + 1) & 1) * 4096;
      const u16* gk0 = kbase + (size_t)(j0n + w * 8 + jr) * 2048 + ((bk ^ jr) * 8);
      __builtin_amdgcn_global_load_lds(AS1(gk0), AS3(Ksn + w * 512), 16, 0, 0);
      const u16* gk1 = kbase + (size_t)(j0n + 32 + w * 8 + jr) * 2048 + ((bk ^ jr) * 8);
      __builtin_amdgcn_global_load_lds(AS1(gk1), AS3(Ksn + 2048 + w * 512), 16, 0, 0);
      vregA = *(const uint4*)(vbase + (size_t)(j0n + (tid >> 3)) * 2048 + (tid & 7) * 8);
      vregB = *(const uint4*)(vbase + (size_t)(j0n + 32 + (tid >> 3)) * 2048 + (tid & 7) * 8);
    }
  };

  auto qkt = [&](int t, f32x16& n0, f32x16& n1) {
    const u16* Ksc = Ks + (t & 1) * 4096;
#pragma unroll
    for (int r = 0; r < 16; ++r) { n0[r] = 0.f; n1[r] = 0.f; }
    int swk = (li & 7) << 4;
    __builtin_amdgcn_s_setprio(1);
#pragma unroll
    for (int kb = 0; kb < 4; ++kb) {
      bf16x8 k0 = *(const bf16x8*)((const char*)Ksc + li * 128        + ((kb * 32 + hi * 16) ^ swk));
      bf16x8 k1 = *(const bf16x8*)((const char*)Ksc + (32 + li) * 128 + ((kb * 32 + hi * 16) ^ swk));
      bf16x8 qq = (kb == 0) ? qf0 : (kb == 1) ? qf1 : (kb == 2) ? qf2 : qf3;
      n0 = __builtin_amdgcn_mfma_f32_32x32x16_bf16(k0, qq, n0, 0, 0, 0);
      n1 = __builtin_amdgcn_mfma_f32_32x32x16_bf16(k1, qq, n1, 0, 0, 0);
    }
    __builtin_amdgcn_s_setprio(0);
  };

  auto finish_pv = [&](int tp, const f32x16& sp0, const f32x16& sp1) {
    const u16* Vtp = Vt + (tp & 1) * 4096;
    float p0[16], p1[16];
    float sum = 0.f;
#pragma unroll
    for (int r = 0; r < 16; ++r) { p0[r] = exp2_fast(sp0[r] - m_run); sum += p0[r]; }
#pragma unroll
    for (int r = 0; r < 16; ++r) { p1[r] = exp2_fast(sp1[r] - m_run); sum += p1[r]; }
    sum += __shfl_xor(sum, 32);
    l_run += sum;
    unsigned pw[16];
#pragma unroll
    for (int i2 = 0; i2 < 8; ++i2) {
      asm("v_cvt_pk_bf16_f32 %0, %1, %2" : "=v"(pw[i2])     : "v"(p0[2 * i2]), "v"(p0[2 * i2 + 1]));
      asm("v_cvt_pk_bf16_f32 %0, %1, %2" : "=v"(pw[8 + i2]) : "v"(p1[2 * i2]), "v"(p1[2 * i2 + 1]));
    }
#pragma unroll
    for (int gB = 0; gB < 2; ++gB) {
      int o = gB * 8;
      asm volatile("v_permlane32_swap_b32 %0, %1" : "+v"(pw[o + 0]), "+v"(pw[o + 2]));
      asm volatile("v_permlane32_swap_b32 %0, %1" : "+v"(pw[o + 1]), "+v"(pw[o + 3]));
      asm volatile("v_permlane32_swap_b32 %0, %1" : "+v"(pw[o + 4]), "+v"(pw[o + 6]));
      asm volatile("v_permlane32_swap_b32 %0, %1" : "+v"(pw[o + 5]), "+v"(pw[o + 7]));
    }
    __builtin_amdgcn_s_setprio(1);
#pragma unroll
    for (int kb2 = 0; kb2 < 4; ++kb2) {
      uint4 ufr;
      ufr.x = pw[kb2 * 4 + 0]; ufr.y = pw[kb2 * 4 + 1];
      ufr.z = pw[kb2 * 4 + 2]; ufr.w = pw[kb2 * 4 + 3];
      bf16x8 pa = *(bf16x8*)&ufr;
      int jbyte = kb2 * 32 + hi * 16;
      int d0_ = li, d1_ = 32 + li;
      bf16x8 v0 = *(const bf16x8*)((const char*)Vtp + d0_ * 128 + (jbyte ^ (((d0_ ^ (d0_ >> 3)) & 7) << 4)));
      bf16x8 v1 = *(const bf16x8*)((const char*)Vtp + d1_ * 128 + (jbyte ^ (((d1_ ^ (d1_ >> 3)) & 7) << 4)));
      acc0 = __builtin_amdgcn_mfma_f32_32x32x16_bf16(v0, pa, acc0, 0, 0, 0);
      acc1 = __builtin_amdgcn_mfma_f32_32x32x16_bf16(v1, pa, acc1, 0, 0, 0);
    }
    __builtin_amdgcn_s_setprio(0);
  };

  auto maxred = [&](const f32x16& n0, const f32x16& n1) {
    float pm = fmaxf(n0[0], n0[1]);
#pragma unroll
    for (int r = 2; r < 16; r += 2) pm = fmaxf(fmaxf(pm, n0[r]), n0[r + 1]);
#pragma unroll
    for (int r = 0; r < 16; r += 2) pm = fmaxf(fmaxf(pm, n1[r]), n1[r + 1]);
    pm = fmaxf(pm, __shfl_xor(pm, 32));
    if (!__all(pm <= m_run + 8.0f)) {
      float mnew = fmaxf(m_run, pm);
      float esc = exp2_fast(m_run - mnew);
      m_run = mnew;
      l_run *= esc;
#pragma unroll
      for (int r = 0; r < 16; ++r) { acc0[r] *= esc; acc1[r] *= esc; }
    }
  };

  f32x16 sa0, sa1, sb0, sb1;
  __syncthreads();                 // K(0) landed
  stage_pf(0);
  qkt(0, sa0, sa1);
  maxred(sa0, sa1);
  for (int t = 1; t < NT - 1; t += 2) {
    __syncthreads();
    stage_pf(t);
    qkt(t, sb0, sb1);
    finish_pv(t - 1, sa0, sa1);
    maxred(sb0, sb1);
    __syncthreads();
    stage_pf(t + 1);
    qkt(t + 1, sa0, sa1);
    finish_pv(t, sb0, sb1);
    maxred(sa0, sa1);
  }
  __syncthreads();
  stage_pf(NT - 1);
  qkt(NT - 1, sb0, sb1);
  finish_pv(NT - 2, sa0, sa1);
  maxred(sb0, sb1);
  __syncthreads();
  finish_pv(NT - 1, sb0, sb1);

  float inv = 1.f / l_run;
  float* orow = O + ((size_t)(b * SQ + i0g + li) * 1024 + h * 64);
#pragma unroll
  for (int g = 0; g < 4; ++g) {
    f32x4 o0, o1;
#pragma unroll
    for (int q_ = 0; q_ < 4; ++q_) {
      o0[q_] = acc0[g * 4 + q_] * inv;
      o1[q_] = acc1[g * 4 + q_] * inv;
    }
    *(f32x4*)(orow + 8 * g + 4 * hi) = o0;
    *(f32x4*)(orow + 32 + 8 * g + 4 * hi) = o1;
  }
}

extern "C" void kernel_launch(void* const* d_in, const int* in_sizes, int n_in,
                              void* d_out, int out_size, void* d_ws, size_t ws_size,
                              hipStream_t stream) {
  (void)in_sizes; (void)n_in; (void)out_size; (void)ws_size;
  const float* x   = (const float*)d_in[0];
  const float* ctx = (const float*)d_in[1];
  const float* Wq  = (const float*)d_in[2];
  const float* Wkv = (const float*)d_in[3];
  float* out = (float*)d_out;
  char* ws = (char*)d_ws;

  u16* q  = (u16*)(ws);                  // q bf16 [4096][1024], pre-scaled by 0.125*log2(e)  8 MB
  u16* kv = (u16*)(ws + (8ull << 20));   // kv bf16 [4096][2048]                              16 MB

  // cast fused into GEMM: reads fp32 inputs directly
  gemm_fused<<<768, 256, 0, stream>>>(x, Wq, q, ctx, Wkv, kv, 0.125f * 1.44269504f);

  attn_kernel<<<512, 256, 0, stream>>>(q, kv, out);
}